// Round 10
// baseline (710.582 us; speedup 1.0000x reference)
//
#include <hip/hip_runtime.h>
#include <stdint.h>

typedef unsigned short u16;
typedef float floatx4 __attribute__((ext_vector_type(4)));
typedef __bf16 bf16x4 __attribute__((ext_vector_type(4)));
typedef __bf16 bf16x8 __attribute__((ext_vector_type(8)));

#define ST 2048
#define SD 512

__device__ __forceinline__ floatx4 mfma16(bf16x8 a, bf16x8 b, floatx4 c) {
  return __builtin_amdgcn_mfma_f32_16x16x32_bf16(a, b, c, 0, 0, 0);
}
__device__ __forceinline__ bf16x8 ld8(const u16* p) {
  return *reinterpret_cast<const bf16x8*>(p);
}
__device__ __forceinline__ u16 f2bf(float f) {
  union { float f; uint32_t u; } v; v.f = f;
  uint32_t r = v.u + 0x7FFFu + ((v.u >> 16) & 1u);
  return (u16)(r >> 16);
}
__device__ __forceinline__ float bf2f(u16 h) {
  union { uint32_t u; float f; } v; v.u = ((uint32_t)h) << 16; return v.f;
}
__device__ __forceinline__ bf16x8 cvt2bf8(floatx4 a, floatx4 b) {
  bf16x4 lo = __builtin_convertvector(a, bf16x4);
  bf16x4 hi = __builtin_convertvector(b, bf16x4);
  bf16x8 r;
  r[0] = lo[0]; r[1] = lo[1]; r[2] = lo[2]; r[3] = lo[3];
  r[4] = hi[0]; r[5] = hi[1]; r[6] = hi[2]; r[7] = hi[3];
  return r;
}
// async global->LDS, 16 B per lane; LDS dst = wave-uniform base + lane*16
__device__ __forceinline__ void gl2lds(const u16* g, u16* l) {
  __builtin_amdgcn_global_load_lds(
      (const __attribute__((address_space(1))) unsigned int*)g,
      (__attribute__((address_space(3))) unsigned int*)l, 16, 0, 0);
}

// ---- x concat + cast: xc[m][k] bf16
__global__ __launch_bounds__(256) void xcast(const float* __restrict__ x0,
                                             const float* __restrict__ x1,
                                             u16* __restrict__ xc) {
  size_t f = ((size_t)blockIdx.x * 256 + threadIdx.x) * 8;
  int m = (int)(f >> 10), k = (int)(f & 1023);
  const float* src = (k < SD) ? (x0 + (size_t)m * SD + k)
                              : (x1 + (size_t)m * SD + (k - SD));
  floatx4 a = *reinterpret_cast<const floatx4*>(src);
  floatx4 b = *reinterpret_cast<const floatx4*>(src + 4);
  *reinterpret_cast<bf16x8*>(xc + f) = cvt2bf8(a, b);
}

// ---- W transpose+cast: f32 [1024,512] -> bf16 [512,1024] x3 (stacked rows 0..1535)
__global__ void wtrans(const float* __restrict__ wq, const float* __restrict__ wk,
                       const float* __restrict__ wv, u16* __restrict__ wt) {
  __shared__ float tile[32][33];
  const float* w = (blockIdx.z == 0) ? wq : (blockIdx.z == 1) ? wk : wv;
  u16* o = wt + (size_t)blockIdx.z * (SD * 1024);
  int k0 = blockIdx.x * 32, n0 = blockIdx.y * 32;
  int tx = threadIdx.x, ty = threadIdx.y;
#pragma unroll
  for (int i = 0; i < 32; i += 8)
    tile[ty + i][tx] = w[(size_t)(k0 + ty + i) * SD + n0 + tx];
  __syncthreads();
#pragma unroll
  for (int i = 0; i < 32; i += 8)
    o[(size_t)(n0 + ty + i) * 1024 + k0 + tx] = f2bf(tile[tx][ty + i]);
}

// ---- QKV as one m97-style GEMM: C[16384 x 1536] = xc . wt^T (unchanged)
__global__ __launch_bounds__(256, 2) void qkv_m97(
    const u16* __restrict__ xc, const u16* __restrict__ wt,
    u16* __restrict__ qb, u16* __restrict__ kk, u16* __restrict__ vt) {
  __shared__ __align__(16) u16 lA[2][128 * 32];
  __shared__ __align__(16) u16 lB[2][128 * 32];
  int tid = threadIdx.x;
  int wave = tid >> 6, lane = tid & 63;
  int quad = lane >> 4, l16 = lane & 15;
  int m0 = blockIdx.x * 128;
  int n0 = blockIdx.y * 128;
  int wm = (wave & 1) * 64, wn = (wave >> 1) * 64;
  int srow = lane >> 2, schunk = lane & 3;
  int fsw = (l16 >> 1) & 3;

  floatx4 zero = {0.f, 0.f, 0.f, 0.f};
  floatx4 acc[4][4];
#pragma unroll
  for (int i = 0; i < 4; ++i)
#pragma unroll
    for (int j = 0; j < 4; ++j) acc[i][j] = zero;

#define QKV_STAGE(K0, BUF)                                                     \
  {                                                                            \
    _Pragma("unroll") for (int i = 0; i < 2; ++i) {                            \
      int r0 = (i * 4 + wave) * 16;                                            \
      int ra = r0 + srow;                                                      \
      int gc = schunk ^ ((srow >> 1) & 3);                                     \
      gl2lds(xc + (size_t)(m0 + ra) * 1024 + (K0) + gc * 8, &lA[BUF][r0 * 32]);\
      gl2lds(wt + (size_t)(n0 + ra) * 1024 + (K0) + gc * 8, &lB[BUF][r0 * 32]);\
    }                                                                          \
  }

  QKV_STAGE(0, 0);
#pragma unroll 1
  for (int it = 0; it < 32; ++it) {
    __syncthreads();
    if (it + 1 < 32) QKV_STAGE((it + 1) * 32, (it + 1) & 1);
    int buf = it & 1;
    bf16x8 fa[4], fb[4];
#pragma unroll
    for (int t = 0; t < 4; ++t) {
      int ra = wm + t * 16 + l16;
      fa[t] = ld8(&lA[buf][ra * 32 + (quad ^ fsw) * 8]);
      int rb = wn + t * 16 + l16;
      fb[t] = ld8(&lB[buf][rb * 32 + (quad ^ fsw) * 8]);
    }
#pragma unroll
    for (int mt = 0; mt < 4; ++mt)
#pragma unroll
      for (int nt = 0; nt < 4; ++nt)
        acc[mt][nt] = mfma16(fa[mt], fb[nt], acc[mt][nt]);
  }

#pragma unroll
  for (int nt = 0; nt < 4; ++nt) {
    int ng = n0 + wn + nt * 16 + l16;
    int z = ng >> 9, col = ng & 511;
#pragma unroll
    for (int mt = 0; mt < 4; ++mt) {
#pragma unroll
      for (int r = 0; r < 4; ++r) {
        int m = m0 + wm + mt * 16 + quad * 4 + r;
        u16 h = f2bf(acc[mt][nt][r]);
        if (z == 0) qb[(size_t)m * SD + col] = h;
        else if (z == 1) kk[(size_t)m * SD + col] = h;
        else {
          int bb = m >> 11, t = m & 2047;
          vt[((size_t)bb * SD + col) * ST + t] = h;
        }
      }
    }
  }
}

// ---- Flash attention partials. Complementary job permutation:
// lower 256 blocks: half A of tile (31 - j>>3)  -> 32 - (j>>3) chunks
// upper 256 blocks: half B of tile (j>>3)       -> (j>>3) + 1 chunks
// => blocks c and c+256 sum to 33 chunks (uniform per-CU under round-robin).
// NO VGPR clamp (R9's launch_bounds(256,2) forced 128 VGPR -> acc spilled).
__global__ __launch_bounds__(256) void attn_part(
    const u16* __restrict__ qb, const u16* __restrict__ kk,
    const u16* __restrict__ vt, u16* __restrict__ pacc,
    float* __restrict__ pml) {
  __shared__ __align__(16) u16 lK[2][32 * 512];   // [s][d], 64 KB
  __shared__ __align__(16) u16 plds[4][16 * 40];  // per-wave P
  int tid = threadIdx.x;
  int wave = tid >> 6, lane = tid & 63;
  int quad = lane >> 4, l16 = lane & 15;
  int j = blockIdx.x & 255;
  int hi = blockIdx.x >> 8;
  int b = j & 7;
  int tj = j >> 3;                       // 0..31
  int tt = hi ? tj : (31 - tj);
  int half = hi;
  int t0 = tt * 64;
  int t0w = t0 + wave * 16;
  int smaxw = t0w + 15;
  int c0 = half ? (tt + 1) : 0;
  int c1 = half ? (2 * tt + 2) : (tt + 1);
  int job = ((b * 32 + tt) * 2 + half);
  const float scale = 0.044194173824159216f;  // 512^-0.5
  const u16* kb0 = kk + (size_t)b * ST * SD;
  const u16* vb0 = vt + (size_t)b * SD * ST;
  u16* myp = &plds[wave][0];

#define PART_STAGE(CH)                                                         \
  {                                                                            \
    int _buf = (CH)&1;                                                         \
    int _s0 = (CH)*32;                                                         \
    _Pragma("unroll") for (int i = 0; i < 8; ++i) {                            \
      int r = i * 4 + wave;                                                    \
      gl2lds(kb0 + (size_t)(_s0 + r) * SD + ((lane ^ (r & 7)) * 8),            \
             &lK[_buf][r * 512]);                                              \
    }                                                                          \
  }

  PART_STAGE(c0);

  const u16* qp = qb + (size_t)(b * ST + t0w + l16) * SD + quad * 8;
  bf16x8 qf[16];
#pragma unroll
  for (int c = 0; c < 16; ++c) qf[c] = ld8(qp + c * 32);

  floatx4 zero = {0.f, 0.f, 0.f, 0.f};
  floatx4 acc[32];
#pragma unroll
  for (int i = 0; i < 32; ++i) acc[i] = zero;
  float mrow[4] = {-1e30f, -1e30f, -1e30f, -1e30f};
  float lrow[4] = {0.f, 0.f, 0.f, 0.f};
  int ksw = l16 & 7;

#pragma unroll 1
  for (int ch = c0; ch < c1; ++ch) {
    __syncthreads();  // chunk ch staged; buffer (ch+1)&1 free
    if (ch + 1 < c1) PART_STAGE(ch + 1);
    int s0 = ch * 32;
    if (s0 > smaxw) continue;  // fully masked for this wave's rows (half B tail)
    int buf = ch & 1;
    const u16* lKb = &lK[buf][0];
    bool diag = (s0 + 31) > t0w;

    floatx4 sacc[2] = {zero, zero};
#pragma unroll
    for (int c = 0; c < 16; ++c) {
      bf16x8 a = qf[c];
#pragma unroll
      for (int nt = 0; nt < 2; ++nt) {
        int sr = nt * 16 + l16;
        bf16x8 fb = ld8(lKb + sr * 512 + (((c * 4 + quad) ^ ksw) * 8));
        sacc[nt] = mfma16(a, fb, sacc[nt]);
      }
    }
#pragma unroll
    for (int nt = 0; nt < 2; ++nt) {
#pragma unroll
      for (int r = 0; r < 4; ++r) {
        float sv = sacc[nt][r] * scale;
        if (diag) {
          int sg = s0 + nt * 16 + l16;
          int tg = t0w + quad * 4 + r;
          sv = (sg > tg) ? -1e30f : sv;
        }
        sacc[nt][r] = sv;
      }
    }
    float mnew[4], alpha[4];
#pragma unroll
    for (int r = 0; r < 4; ++r) {
      float mx = fmaxf(sacc[0][r], sacc[1][r]);
      mx = fmaxf(mx, __shfl_xor(mx, 1));
      mx = fmaxf(mx, __shfl_xor(mx, 2));
      mx = fmaxf(mx, __shfl_xor(mx, 4));
      mx = fmaxf(mx, __shfl_xor(mx, 8));
      float mn = fmaxf(mrow[r], mx);
      alpha[r] = __expf(mrow[r] - mn);
      mnew[r] = mn;
      mrow[r] = mn;
    }
#pragma unroll
    for (int r = 0; r < 4; ++r) {
      float rs = 0.f;
#pragma unroll
      for (int nt = 0; nt < 2; ++nt) {
        float p = __expf(sacc[nt][r] - mnew[r]);  // masked -> exactly 0
        rs += p;
        myp[(quad * 4 + r) * 40 + nt * 16 + l16] = f2bf(p);
      }
      rs += __shfl_xor(rs, 1);
      rs += __shfl_xor(rs, 2);
      rs += __shfl_xor(rs, 4);
      rs += __shfl_xor(rs, 8);
      lrow[r] = lrow[r] * alpha[r] + rs;
    }
#pragma unroll
    for (int nt = 0; nt < 32; ++nt)
#pragma unroll
      for (int r = 0; r < 4; ++r) acc[nt][r] *= alpha[r];
    // PV: P via wave-private LDS; V direct from global (vt[d][t])
    bf16x8 pf = ld8(myp + l16 * 40 + quad * 8);
    const u16* vb = vb0 + s0 + quad * 8;
#pragma unroll
    for (int nt = 0; nt < 32; ++nt) {
      bf16x8 vf = ld8(vb + (size_t)(nt * 16 + l16) * ST);
      acc[nt] = mfma16(pf, vf, acc[nt]);
    }
  }

  // write partials: raw acc (bf16) + m,l per row
  u16* pj = pacc + (size_t)job * (64 * 512);
#pragma unroll
  for (int r = 0; r < 4; ++r) {
    int row = wave * 16 + quad * 4 + r;
    if (l16 == 0) {
      pml[job * 128 + row * 2 + 0] = mrow[r];
      pml[job * 128 + row * 2 + 1] = lrow[r];
    }
    u16* prow = pj + (size_t)row * 512;
#pragma unroll
    for (int nt = 0; nt < 32; ++nt)
      prow[nt * 16 + l16] = f2bf(acc[nt][r]);
  }
}

// ---- block reductions (256 threads = 4 waves)
__device__ __forceinline__ float blk_sum(float v, volatile float* red, int tid) {
#pragma unroll
  for (int o = 1; o < 64; o <<= 1) v += __shfl_xor(v, o);
  __syncthreads();
  if ((tid & 63) == 0) red[tid >> 6] = v;
  __syncthreads();
  return red[0] + red[1] + red[2] + red[3];
}

// ---- merge two s-halves + LayerNorm. One block per (b,t) row.
__global__ __launch_bounds__(256) void attn_merge(
    const u16* __restrict__ pacc, const float* __restrict__ pml,
    const float* __restrict__ gamma, const float* __restrict__ beta,
    float* __restrict__ out) {
  __shared__ float red[4];
  int t = blockIdx.x, b = blockIdx.y;
  int tid = threadIdx.x;
  int tt = t >> 6, row = t & 63;
  int jobA = (b * 32 + tt) * 2, jobB = jobA + 1;
  float mA = pml[jobA * 128 + row * 2], lA = pml[jobA * 128 + row * 2 + 1];
  float mB = pml[jobB * 128 + row * 2], lB = pml[jobB * 128 + row * 2 + 1];
  float m = fmaxf(mA, mB);
  float eA = __expf(mA - m), eB = __expf(mB - m);
  float invl = 1.0f / (eA * lA + eB * lB);
  const u16* pa = pacc + (size_t)jobA * (64 * 512) + (size_t)row * 512;
  const u16* pb = pacc + (size_t)jobB * (64 * 512) + (size_t)row * 512;
  int c0 = tid * 2;
  float o0 = (eA * bf2f(pa[c0]) + eB * bf2f(pb[c0])) * invl;
  float o1 = (eA * bf2f(pa[c0 + 1]) + eB * bf2f(pb[c0 + 1])) * invl;
  float s1 = blk_sum(o0 + o1, red, tid);
  __syncthreads();
  float s2 = blk_sum(o0 * o0 + o1 * o1, red, tid);
  float mu = s1 * (1.f / 512.f);
  float var = s2 * (1.f / 512.f) - mu * mu;
  float rstd = rsqrtf(var + 1e-5f);
  float* orow = out + ((size_t)b * ST + t) * SD;
  orow[c0]     = (o0 - mu) * rstd * gamma[c0] + beta[c0];
  orow[c0 + 1] = (o1 - mu) * rstd * gamma[c0 + 1] + beta[c0 + 1];
}

extern "C" void kernel_launch(void* const* d_in, const int* in_sizes, int n_in,
                              void* d_out, int out_size, void* d_ws, size_t ws_size,
                              hipStream_t stream) {
  (void)in_sizes; (void)n_in; (void)out_size; (void)ws_size;
  const float* x0 = (const float*)d_in[0];
  const float* x1 = (const float*)d_in[1];
  const float* Wq = (const float*)d_in[2];
  const float* Wk = (const float*)d_in[3];
  const float* Wv = (const float*)d_in[4];
  const float* gamma = (const float*)d_in[5];
  const float* beta = (const float*)d_in[6];
  u16* ws = (u16*)d_ws;
  u16* wt = ws;                                // 3*512*1024   ( 3.1 MB)
  u16* qb = wt + (size_t)3 * 512 * 1024;       // 16384*512    (16.8 MB)
  u16* kk = qb + (size_t)16384 * 512;          // 16384*512    (16.8 MB)
  u16* vt = kk + (size_t)16384 * 512;          // 8*512*2048   (16.8 MB)
  u16* xc = vt + (size_t)8 * 512 * 2048;       // 16384*1024   (33.6 MB)
  u16* pacc = xc;                              // reuse xc after qkv (same size)
  float* pml = (float*)wt;                     // reuse wt after qkv (0.26 MB)
  float* out = (float*)d_out;

  xcast<<<dim3(8192), dim3(256), 0, stream>>>(x0, x1, xc);
  wtrans<<<dim3(32, 16, 3), dim3(32, 8), 0, stream>>>(Wq, Wk, Wv, wt);
  qkv_m97<<<dim3(128, 12), dim3(256), 0, stream>>>(xc, wt, qb, kk, vt);
  attn_part<<<dim3(512), dim3(256), 0, stream>>>(qb, kk, vt, pacc, pml);
  attn_merge<<<dim3(2048, 8), dim3(256), 0, stream>>>(pacc, pml, gamma, beta, out);
}

// Round 11
// 370.702 us; speedup vs baseline: 1.9169x; 1.9169x over previous
//
#include <hip/hip_runtime.h>
#include <stdint.h>

typedef unsigned short u16;
typedef float floatx4 __attribute__((ext_vector_type(4)));
typedef __bf16 bf16x4 __attribute__((ext_vector_type(4)));
typedef __bf16 bf16x8 __attribute__((ext_vector_type(8)));

#define ST 2048
#define SD 512

__device__ __forceinline__ floatx4 mfma16(bf16x8 a, bf16x8 b, floatx4 c) {
  return __builtin_amdgcn_mfma_f32_16x16x32_bf16(a, b, c, 0, 0, 0);
}
__device__ __forceinline__ bf16x8 ld8(const u16* p) {
  return *reinterpret_cast<const bf16x8*>(p);
}
__device__ __forceinline__ u16 f2bf(float f) {
  union { float f; uint32_t u; } v; v.f = f;
  uint32_t r = v.u + 0x7FFFu + ((v.u >> 16) & 1u);
  return (u16)(r >> 16);
}
__device__ __forceinline__ float bf2f(u16 h) {
  union { uint32_t u; float f; } v; v.u = ((uint32_t)h) << 16; return v.f;
}
__device__ __forceinline__ bf16x8 cvt2bf8(floatx4 a, floatx4 b) {
  bf16x4 lo = __builtin_convertvector(a, bf16x4);
  bf16x4 hi = __builtin_convertvector(b, bf16x4);
  bf16x8 r;
  r[0] = lo[0]; r[1] = lo[1]; r[2] = lo[2]; r[3] = lo[3];
  r[4] = hi[0]; r[5] = hi[1]; r[6] = hi[2]; r[7] = hi[3];
  return r;
}
// async global->LDS, 16 B per lane; LDS dst = wave-uniform base + lane*16
__device__ __forceinline__ void gl2lds(const u16* g, u16* l) {
  __builtin_amdgcn_global_load_lds(
      (const __attribute__((address_space(1))) unsigned int*)g,
      (__attribute__((address_space(3))) unsigned int*)l, 16, 0, 0);
}

// ---- x concat + cast: xc[m][k] bf16
__global__ __launch_bounds__(256) void xcast(const float* __restrict__ x0,
                                             const float* __restrict__ x1,
                                             u16* __restrict__ xc) {
  size_t f = ((size_t)blockIdx.x * 256 + threadIdx.x) * 8;
  int m = (int)(f >> 10), k = (int)(f & 1023);
  const float* src = (k < SD) ? (x0 + (size_t)m * SD + k)
                              : (x1 + (size_t)m * SD + (k - SD));
  floatx4 a = *reinterpret_cast<const floatx4*>(src);
  floatx4 b = *reinterpret_cast<const floatx4*>(src + 4);
  *reinterpret_cast<bf16x8*>(xc + f) = cvt2bf8(a, b);
}

// ---- W transpose+cast: f32 [1024,512] -> bf16 [512,1024] x3 (stacked rows 0..1535)
__global__ void wtrans(const float* __restrict__ wq, const float* __restrict__ wk,
                       const float* __restrict__ wv, u16* __restrict__ wt) {
  __shared__ float tile[32][33];
  const float* w = (blockIdx.z == 0) ? wq : (blockIdx.z == 1) ? wk : wv;
  u16* o = wt + (size_t)blockIdx.z * (SD * 1024);
  int k0 = blockIdx.x * 32, n0 = blockIdx.y * 32;
  int tx = threadIdx.x, ty = threadIdx.y;
#pragma unroll
  for (int i = 0; i < 32; i += 8)
    tile[ty + i][tx] = w[(size_t)(k0 + ty + i) * SD + n0 + tx];
  __syncthreads();
#pragma unroll
  for (int i = 0; i < 32; i += 8)
    o[(size_t)(n0 + ty + i) * 1024 + k0 + tx] = f2bf(tile[tx][ty + i]);
}

// ---- QKV as one m97-style GEMM: C[16384 x 1536] = xc . wt^T (unchanged)
__global__ __launch_bounds__(256, 2) void qkv_m97(
    const u16* __restrict__ xc, const u16* __restrict__ wt,
    u16* __restrict__ qb, u16* __restrict__ kk, u16* __restrict__ vt) {
  __shared__ __align__(16) u16 lA[2][128 * 32];
  __shared__ __align__(16) u16 lB[2][128 * 32];
  int tid = threadIdx.x;
  int wave = tid >> 6, lane = tid & 63;
  int quad = lane >> 4, l16 = lane & 15;
  int m0 = blockIdx.x * 128;
  int n0 = blockIdx.y * 128;
  int wm = (wave & 1) * 64, wn = (wave >> 1) * 64;
  int srow = lane >> 2, schunk = lane & 3;
  int fsw = (l16 >> 1) & 3;

  floatx4 zero = {0.f, 0.f, 0.f, 0.f};
  floatx4 acc[4][4];
#pragma unroll
  for (int i = 0; i < 4; ++i)
#pragma unroll
    for (int j = 0; j < 4; ++j) acc[i][j] = zero;

#define QKV_STAGE(K0, BUF)                                                     \
  {                                                                            \
    _Pragma("unroll") for (int i = 0; i < 2; ++i) {                            \
      int r0 = (i * 4 + wave) * 16;                                            \
      int ra = r0 + srow;                                                      \
      int gc = schunk ^ ((srow >> 1) & 3);                                     \
      gl2lds(xc + (size_t)(m0 + ra) * 1024 + (K0) + gc * 8, &lA[BUF][r0 * 32]);\
      gl2lds(wt + (size_t)(n0 + ra) * 1024 + (K0) + gc * 8, &lB[BUF][r0 * 32]);\
    }                                                                          \
  }

  QKV_STAGE(0, 0);
#pragma unroll 1
  for (int it = 0; it < 32; ++it) {
    __syncthreads();
    if (it + 1 < 32) QKV_STAGE((it + 1) * 32, (it + 1) & 1);
    int buf = it & 1;
    bf16x8 fa[4], fb[4];
#pragma unroll
    for (int t = 0; t < 4; ++t) {
      int ra = wm + t * 16 + l16;
      fa[t] = ld8(&lA[buf][ra * 32 + (quad ^ fsw) * 8]);
      int rb = wn + t * 16 + l16;
      fb[t] = ld8(&lB[buf][rb * 32 + (quad ^ fsw) * 8]);
    }
#pragma unroll
    for (int mt = 0; mt < 4; ++mt)
#pragma unroll
      for (int nt = 0; nt < 4; ++nt)
        acc[mt][nt] = mfma16(fa[mt], fb[nt], acc[mt][nt]);
  }

#pragma unroll
  for (int nt = 0; nt < 4; ++nt) {
    int ng = n0 + wn + nt * 16 + l16;
    int z = ng >> 9, col = ng & 511;
#pragma unroll
    for (int mt = 0; mt < 4; ++mt) {
#pragma unroll
      for (int r = 0; r < 4; ++r) {
        int m = m0 + wm + mt * 16 + quad * 4 + r;
        u16 h = f2bf(acc[mt][nt][r]);
        if (z == 0) qb[(size_t)m * SD + col] = h;
        else if (z == 1) kk[(size_t)m * SD + col] = h;
        else {
          int bb = m >> 11, t = m & 2047;
          vt[((size_t)bb * SD + col) * ST + t] = h;
        }
      }
    }
  }
}

// ---- Flash attention partials: EXACT R8 attn3 body (dbuf K+V in LDS, proven
// 4.2 us/chunk), with the s-range halved into 2 jobs per tile (tt+1 chunks
// each). Heavy-first; HW backfill gives ~33 chunk-times/CU vs 64. No VGPR clamp.
__global__ __launch_bounds__(256) void attn_part(
    const u16* __restrict__ qb, const u16* __restrict__ kk,
    const u16* __restrict__ vt, u16* __restrict__ pacc,
    float* __restrict__ pml) {
  __shared__ __align__(16) u16 lK[2][32 * 512];   // [s][d], 2x32 KB
  __shared__ __align__(16) u16 lV[2][512 * 32];   // [d][s], 2x32 KB
  __shared__ __align__(16) u16 plds[4][16 * 40];  // per-wave P
  int tid = threadIdx.x;
  int wave = tid >> 6, lane = tid & 63;
  int quad = lane >> 4, l16 = lane & 15;
  int b = blockIdx.x & 7;                   // XCD/L2 locality
  int half = (blockIdx.x >> 3) & 1;
  int tt = 31 - (blockIdx.x >> 4);          // heavy tiles first
  int t0 = tt * 64;
  int t0w = t0 + wave * 16;
  int smaxw = t0w + 15;
  int c0 = half ? (tt + 1) : 0;
  int c1 = half ? (2 * tt + 2) : (tt + 1);
  int job = ((b * 32 + tt) * 2 + half);
  const float scale = 0.044194173824159216f;  // 512^-0.5
  const u16* kb0 = kk + (size_t)b * ST * SD;
  const u16* vb0 = vt + (size_t)b * SD * ST;
  u16* myp = &plds[wave][0];
  int srow = lane >> 2, schunk = lane & 3;
  int ksw = l16 & 7;          // K frag-read swizzle (s-row & 7)
  int vsw = (l16 >> 1) & 3;   // V frag-read swizzle ((d>>1)&3)

#define PART_STAGE(CH)                                                         \
  {                                                                            \
    int _buf = (CH)&1;                                                         \
    int _s0 = (CH)*32;                                                         \
    _Pragma("unroll") for (int i = 0; i < 8; ++i) {                            \
      int r = i * 4 + wave;                                                    \
      gl2lds(kb0 + (size_t)(_s0 + r) * SD + ((lane ^ (r & 7)) * 8),            \
             &lK[_buf][r * 512]);                                              \
    }                                                                          \
    _Pragma("unroll") for (int i = 0; i < 8; ++i) {                            \
      int d0 = (i * 4 + wave) * 16;                                            \
      int d = d0 + srow;                                                       \
      gl2lds(vb0 + (size_t)d * ST + _s0 + ((schunk ^ ((srow >> 1) & 3)) * 8),  \
             &lV[_buf][d0 * 32]);                                              \
    }                                                                          \
  }

  PART_STAGE(c0);

  const u16* qp = qb + (size_t)(b * ST + t0w + l16) * SD + quad * 8;
  bf16x8 qf[16];
#pragma unroll
  for (int c = 0; c < 16; ++c) qf[c] = ld8(qp + c * 32);

  floatx4 zero = {0.f, 0.f, 0.f, 0.f};
  floatx4 acc[32];
#pragma unroll
  for (int i = 0; i < 32; ++i) acc[i] = zero;
  float mrow[4] = {-1e30f, -1e30f, -1e30f, -1e30f};
  float lrow[4] = {0.f, 0.f, 0.f, 0.f};

#pragma unroll 1
  for (int ch = c0; ch < c1; ++ch) {
    __syncthreads();  // chunk ch staged; buffer (ch+1)&1 free
    if (ch + 1 < c1) PART_STAGE(ch + 1);
    int s0 = ch * 32;
    if (s0 > smaxw) continue;  // fully masked for this wave's rows
    int buf = ch & 1;
    const u16* lKb = &lK[buf][0];
    const u16* lVb = &lV[buf][0];
    bool diag = (s0 + 31) > t0w;

    floatx4 sacc[2] = {zero, zero};
#pragma unroll
    for (int c = 0; c < 16; ++c) {
      bf16x8 a = qf[c];
#pragma unroll
      for (int nt = 0; nt < 2; ++nt) {
        int sr = nt * 16 + l16;
        bf16x8 fb = ld8(lKb + sr * 512 + (((c * 4 + quad) ^ ksw) * 8));
        sacc[nt] = mfma16(a, fb, sacc[nt]);
      }
    }
#pragma unroll
    for (int nt = 0; nt < 2; ++nt) {
#pragma unroll
      for (int r = 0; r < 4; ++r) {
        float sv = sacc[nt][r] * scale;
        if (diag) {
          int sg = s0 + nt * 16 + l16;
          int tg = t0w + quad * 4 + r;
          sv = (sg > tg) ? -1e30f : sv;
        }
        sacc[nt][r] = sv;
      }
    }
    float mnew[4], alpha[4];
#pragma unroll
    for (int r = 0; r < 4; ++r) {
      float mx = fmaxf(sacc[0][r], sacc[1][r]);
      mx = fmaxf(mx, __shfl_xor(mx, 1));
      mx = fmaxf(mx, __shfl_xor(mx, 2));
      mx = fmaxf(mx, __shfl_xor(mx, 4));
      mx = fmaxf(mx, __shfl_xor(mx, 8));
      float mn = fmaxf(mrow[r], mx);
      alpha[r] = __expf(mrow[r] - mn);
      mnew[r] = mn;
      mrow[r] = mn;
    }
#pragma unroll
    for (int r = 0; r < 4; ++r) {
      float rs = 0.f;
#pragma unroll
      for (int nt = 0; nt < 2; ++nt) {
        float p = __expf(sacc[nt][r] - mnew[r]);  // masked -> exactly 0
        rs += p;
        myp[(quad * 4 + r) * 40 + nt * 16 + l16] = f2bf(p);
      }
      rs += __shfl_xor(rs, 1);
      rs += __shfl_xor(rs, 2);
      rs += __shfl_xor(rs, 4);
      rs += __shfl_xor(rs, 8);
      lrow[r] = lrow[r] * alpha[r] + rs;
    }
#pragma unroll
    for (int nt = 0; nt < 32; ++nt)
#pragma unroll
      for (int r = 0; r < 4; ++r) acc[nt][r] *= alpha[r];
    // P C-layout -> A-layout via wave-private LDS; V from LDS (staged)
    bf16x8 pf = ld8(myp + l16 * 40 + quad * 8);
#pragma unroll
    for (int nt = 0; nt < 32; ++nt) {
      int dr = nt * 16 + l16;
      bf16x8 vf = ld8(lVb + dr * 32 + ((quad ^ vsw) * 8));
      acc[nt] = mfma16(pf, vf, acc[nt]);
    }
  }

  // write partials: raw acc (bf16) + m,l per row
  u16* pj = pacc + (size_t)job * (64 * 512);
#pragma unroll
  for (int r = 0; r < 4; ++r) {
    int row = wave * 16 + quad * 4 + r;
    if (l16 == 0) {
      pml[job * 128 + row * 2 + 0] = mrow[r];
      pml[job * 128 + row * 2 + 1] = lrow[r];
    }
    u16* prow = pj + (size_t)row * 512;
#pragma unroll
    for (int nt = 0; nt < 32; ++nt)
      prow[nt * 16 + l16] = f2bf(acc[nt][r]);
  }
}

// ---- block reductions (256 threads = 4 waves)
__device__ __forceinline__ float blk_sum(float v, volatile float* red, int tid) {
#pragma unroll
  for (int o = 1; o < 64; o <<= 1) v += __shfl_xor(v, o);
  __syncthreads();
  if ((tid & 63) == 0) red[tid >> 6] = v;
  __syncthreads();
  return red[0] + red[1] + red[2] + red[3];
}

// ---- merge two s-halves + LayerNorm. One block per (b,t) row.
__global__ __launch_bounds__(256) void attn_merge(
    const u16* __restrict__ pacc, const float* __restrict__ pml,
    const float* __restrict__ gamma, const float* __restrict__ beta,
    float* __restrict__ out) {
  __shared__ float red[4];
  int t = blockIdx.x, b = blockIdx.y;
  int tid = threadIdx.x;
  int tt = t >> 6, row = t & 63;
  int jobA = (b * 32 + tt) * 2, jobB = jobA + 1;
  float mA = pml[jobA * 128 + row * 2], lA = pml[jobA * 128 + row * 2 + 1];
  float mB = pml[jobB * 128 + row * 2], lB = pml[jobB * 128 + row * 2 + 1];
  float m = fmaxf(mA, mB);
  float eA = __expf(mA - m), eB = __expf(mB - m);
  float invl = 1.0f / (eA * lA + eB * lB);
  const u16* pa = pacc + (size_t)jobA * (64 * 512) + (size_t)row * 512;
  const u16* pb = pacc + (size_t)jobB * (64 * 512) + (size_t)row * 512;
  int c0 = tid * 2;
  float o0 = (eA * bf2f(pa[c0]) + eB * bf2f(pb[c0])) * invl;
  float o1 = (eA * bf2f(pa[c0 + 1]) + eB * bf2f(pb[c0 + 1])) * invl;
  float s1 = blk_sum(o0 + o1, red, tid);
  __syncthreads();
  float s2 = blk_sum(o0 * o0 + o1 * o1, red, tid);
  float mu = s1 * (1.f / 512.f);
  float var = s2 * (1.f / 512.f) - mu * mu;
  float rstd = rsqrtf(var + 1e-5f);
  float* orow = out + ((size_t)b * ST + t) * SD;
  orow[c0]     = (o0 - mu) * rstd * gamma[c0] + beta[c0];
  orow[c0 + 1] = (o1 - mu) * rstd * gamma[c0 + 1] + beta[c0 + 1];
}

extern "C" void kernel_launch(void* const* d_in, const int* in_sizes, int n_in,
                              void* d_out, int out_size, void* d_ws, size_t ws_size,
                              hipStream_t stream) {
  (void)in_sizes; (void)n_in; (void)out_size; (void)ws_size;
  const float* x0 = (const float*)d_in[0];
  const float* x1 = (const float*)d_in[1];
  const float* Wq = (const float*)d_in[2];
  const float* Wk = (const float*)d_in[3];
  const float* Wv = (const float*)d_in[4];
  const float* gamma = (const float*)d_in[5];
  const float* beta = (const float*)d_in[6];
  u16* ws = (u16*)d_ws;
  u16* wt = ws;                                // 3*512*1024   ( 3.1 MB)
  u16* qb = wt + (size_t)3 * 512 * 1024;       // 16384*512    (16.8 MB)
  u16* kk = qb + (size_t)16384 * 512;          // 16384*512    (16.8 MB)
  u16* vt = kk + (size_t)16384 * 512;          // 8*512*2048   (16.8 MB)
  u16* xc = vt + (size_t)8 * 512 * 2048;       // 16384*1024   (33.6 MB)
  u16* pacc = xc;                              // reuse xc after qkv (same size)
  float* pml = (float*)wt;                     // reuse wt after qkv (0.26 MB)
  float* out = (float*)d_out;

  xcast<<<dim3(8192), dim3(256), 0, stream>>>(x0, x1, xc);
  wtrans<<<dim3(32, 16, 3), dim3(32, 8), 0, stream>>>(Wq, Wk, Wv, wt);
  qkv_m97<<<dim3(128, 12), dim3(256), 0, stream>>>(xc, wt, qb, kk, vt);
  attn_part<<<dim3(512), dim3(256), 0, stream>>>(qb, kk, vt, pacc, pml);
  attn_merge<<<dim3(2048, 8), dim3(256), 0, stream>>>(pacc, pml, gamma, beta, out);
}

// Round 12
// 361.721 us; speedup vs baseline: 1.9644x; 1.0248x over previous
//
#include <hip/hip_runtime.h>
#include <stdint.h>

typedef unsigned short u16;
typedef float floatx4 __attribute__((ext_vector_type(4)));
typedef __bf16 bf16x4 __attribute__((ext_vector_type(4)));
typedef __bf16 bf16x8 __attribute__((ext_vector_type(8)));

#define ST 2048
#define SD 512

__device__ __forceinline__ floatx4 mfma16(bf16x8 a, bf16x8 b, floatx4 c) {
  return __builtin_amdgcn_mfma_f32_16x16x32_bf16(a, b, c, 0, 0, 0);
}
__device__ __forceinline__ bf16x8 ld8(const u16* p) {
  return *reinterpret_cast<const bf16x8*>(p);
}
__device__ __forceinline__ u16 f2bf(float f) {
  union { float f; uint32_t u; } v; v.f = f;
  uint32_t r = v.u + 0x7FFFu + ((v.u >> 16) & 1u);
  return (u16)(r >> 16);
}
__device__ __forceinline__ float bf2f(u16 h) {
  union { uint32_t u; float f; } v; v.u = ((uint32_t)h) << 16; return v.f;
}
__device__ __forceinline__ bf16x8 cvt2bf8(floatx4 a, floatx4 b) {
  bf16x4 lo = __builtin_convertvector(a, bf16x4);
  bf16x4 hi = __builtin_convertvector(b, bf16x4);
  bf16x8 r;
  r[0] = lo[0]; r[1] = lo[1]; r[2] = lo[2]; r[3] = lo[3];
  r[4] = hi[0]; r[5] = hi[1]; r[6] = hi[2]; r[7] = hi[3];
  return r;
}
// async global->LDS, 16 B per lane; LDS dst = wave-uniform base + lane*16
__device__ __forceinline__ void gl2lds(const u16* g, u16* l) {
  __builtin_amdgcn_global_load_lds(
      (const __attribute__((address_space(1))) unsigned int*)g,
      (__attribute__((address_space(3))) unsigned int*)l, 16, 0, 0);
}

// ---- x concat + cast: xc[m][k] bf16
__global__ __launch_bounds__(256) void xcast(const float* __restrict__ x0,
                                             const float* __restrict__ x1,
                                             u16* __restrict__ xc) {
  size_t f = ((size_t)blockIdx.x * 256 + threadIdx.x) * 8;
  int m = (int)(f >> 10), k = (int)(f & 1023);
  const float* src = (k < SD) ? (x0 + (size_t)m * SD + k)
                              : (x1 + (size_t)m * SD + (k - SD));
  floatx4 a = *reinterpret_cast<const floatx4*>(src);
  floatx4 b = *reinterpret_cast<const floatx4*>(src + 4);
  *reinterpret_cast<bf16x8*>(xc + f) = cvt2bf8(a, b);
}

// ---- W transpose+cast: f32 [1024,512] -> bf16 [512,1024] x3 (stacked rows 0..1535)
__global__ void wtrans(const float* __restrict__ wq, const float* __restrict__ wk,
                       const float* __restrict__ wv, u16* __restrict__ wt) {
  __shared__ float tile[32][33];
  const float* w = (blockIdx.z == 0) ? wq : (blockIdx.z == 1) ? wk : wv;
  u16* o = wt + (size_t)blockIdx.z * (SD * 1024);
  int k0 = blockIdx.x * 32, n0 = blockIdx.y * 32;
  int tx = threadIdx.x, ty = threadIdx.y;
#pragma unroll
  for (int i = 0; i < 32; i += 8)
    tile[ty + i][tx] = w[(size_t)(k0 + ty + i) * SD + n0 + tx];
  __syncthreads();
#pragma unroll
  for (int i = 0; i < 32; i += 8)
    o[(size_t)(n0 + ty + i) * 1024 + k0 + tx] = f2bf(tile[tx][ty + i]);
}

// ---- QKV as one m97-style GEMM: C[16384 x 1536] = xc . wt^T (unchanged)
__global__ __launch_bounds__(256, 2) void qkv_m97(
    const u16* __restrict__ xc, const u16* __restrict__ wt,
    u16* __restrict__ qb, u16* __restrict__ kk, u16* __restrict__ vt) {
  __shared__ __align__(16) u16 lA[2][128 * 32];
  __shared__ __align__(16) u16 lB[2][128 * 32];
  int tid = threadIdx.x;
  int wave = tid >> 6, lane = tid & 63;
  int quad = lane >> 4, l16 = lane & 15;
  int m0 = blockIdx.x * 128;
  int n0 = blockIdx.y * 128;
  int wm = (wave & 1) * 64, wn = (wave >> 1) * 64;
  int srow = lane >> 2, schunk = lane & 3;
  int fsw = (l16 >> 1) & 3;

  floatx4 zero = {0.f, 0.f, 0.f, 0.f};
  floatx4 acc[4][4];
#pragma unroll
  for (int i = 0; i < 4; ++i)
#pragma unroll
    for (int j = 0; j < 4; ++j) acc[i][j] = zero;

#define QKV_STAGE(K0, BUF)                                                     \
  {                                                                            \
    _Pragma("unroll") for (int i = 0; i < 2; ++i) {                            \
      int r0 = (i * 4 + wave) * 16;                                            \
      int ra = r0 + srow;                                                      \
      int gc = schunk ^ ((srow >> 1) & 3);                                     \
      gl2lds(xc + (size_t)(m0 + ra) * 1024 + (K0) + gc * 8, &lA[BUF][r0 * 32]);\
      gl2lds(wt + (size_t)(n0 + ra) * 1024 + (K0) + gc * 8, &lB[BUF][r0 * 32]);\
    }                                                                          \
  }

  QKV_STAGE(0, 0);
#pragma unroll 1
  for (int it = 0; it < 32; ++it) {
    __syncthreads();
    if (it + 1 < 32) QKV_STAGE((it + 1) * 32, (it + 1) & 1);
    int buf = it & 1;
    bf16x8 fa[4], fb[4];
#pragma unroll
    for (int t = 0; t < 4; ++t) {
      int ra = wm + t * 16 + l16;
      fa[t] = ld8(&lA[buf][ra * 32 + (quad ^ fsw) * 8]);
      int rb = wn + t * 16 + l16;
      fb[t] = ld8(&lB[buf][rb * 32 + (quad ^ fsw) * 8]);
    }
#pragma unroll
    for (int mt = 0; mt < 4; ++mt)
#pragma unroll
      for (int nt = 0; nt < 4; ++nt)
        acc[mt][nt] = mfma16(fa[mt], fb[nt], acc[mt][nt]);
  }

#pragma unroll
  for (int nt = 0; nt < 4; ++nt) {
    int ng = n0 + wn + nt * 16 + l16;
    int z = ng >> 9, col = ng & 511;
#pragma unroll
    for (int mt = 0; mt < 4; ++mt) {
#pragma unroll
      for (int r = 0; r < 4; ++r) {
        int m = m0 + wm + mt * 16 + quad * 4 + r;
        u16 h = f2bf(acc[mt][nt][r]);
        if (z == 0) qb[(size_t)m * SD + col] = h;
        else if (z == 1) kk[(size_t)m * SD + col] = h;
        else {
          int bb = m >> 11, t = m & 2047;
          vt[((size_t)bb * SD + col) * ST + t] = h;
        }
      }
    }
  }
}

// ---- Flash attention partials. R11 body, but SINGLE-buffered K+V (69 KB LDS
// -> 2 blocks/CU; partner block's waves hide staging latency) + alpha-rescale
// skip (exact: skipped iff all alpha==1.0).
__global__ __launch_bounds__(256) void attn_part(
    const u16* __restrict__ qb, const u16* __restrict__ kk,
    const u16* __restrict__ vt, u16* __restrict__ pacc,
    float* __restrict__ pml) {
  __shared__ __align__(16) u16 lK[32 * 512];      // [s][d], 32 KB
  __shared__ __align__(16) u16 lV[512 * 32];      // [d][s], 32 KB
  __shared__ __align__(16) u16 plds[4][16 * 40];  // per-wave P
  int tid = threadIdx.x;
  int wave = tid >> 6, lane = tid & 63;
  int quad = lane >> 4, l16 = lane & 15;
  int b = blockIdx.x & 7;                   // XCD/L2 locality
  int half = (blockIdx.x >> 3) & 1;
  int tt = 31 - (blockIdx.x >> 4);          // heavy tiles first
  int t0 = tt * 64;
  int t0w = t0 + wave * 16;
  int smaxw = t0w + 15;
  int c0 = half ? (tt + 1) : 0;
  int c1 = half ? (2 * tt + 2) : (tt + 1);
  int job = ((b * 32 + tt) * 2 + half);
  const float scale = 0.044194173824159216f;  // 512^-0.5
  const u16* kb0 = kk + (size_t)b * ST * SD;
  const u16* vb0 = vt + (size_t)b * SD * ST;
  u16* myp = &plds[wave][0];
  int srow = lane >> 2, schunk = lane & 3;
  int ksw = l16 & 7;          // K frag-read swizzle (s-row & 7)
  int vsw = (l16 >> 1) & 3;   // V frag-read swizzle ((d>>1)&3)

#define PART_STAGE(CH)                                                         \
  {                                                                            \
    int _s0 = (CH)*32;                                                         \
    _Pragma("unroll") for (int i = 0; i < 8; ++i) {                            \
      int r = i * 4 + wave;                                                    \
      gl2lds(kb0 + (size_t)(_s0 + r) * SD + ((lane ^ (r & 7)) * 8),            \
             &lK[r * 512]);                                                    \
    }                                                                          \
    _Pragma("unroll") for (int i = 0; i < 8; ++i) {                            \
      int d0 = (i * 4 + wave) * 16;                                            \
      int d = d0 + srow;                                                       \
      gl2lds(vb0 + (size_t)d * ST + _s0 + ((schunk ^ ((srow >> 1) & 3)) * 8),  \
             &lV[d0 * 32]);                                                    \
    }                                                                          \
  }

  PART_STAGE(c0);

  const u16* qp = qb + (size_t)(b * ST + t0w + l16) * SD + quad * 8;
  bf16x8 qf[16];
#pragma unroll
  for (int c = 0; c < 16; ++c) qf[c] = ld8(qp + c * 32);

  floatx4 zero = {0.f, 0.f, 0.f, 0.f};
  floatx4 acc[32];
#pragma unroll
  for (int i = 0; i < 32; ++i) acc[i] = zero;
  float mrow[4] = {-1e30f, -1e30f, -1e30f, -1e30f};
  float lrow[4] = {0.f, 0.f, 0.f, 0.f};

#pragma unroll 1
  for (int ch = c0; ch < c1; ++ch) {
    __syncthreads();  // staging of chunk ch complete (barrier drains vmcnt)
    int s0 = ch * 32;
    if (s0 <= smaxw) {  // wave-level activity; barriers still uniform
      bool diag = (s0 + 31) > t0w;
      floatx4 sacc[2] = {zero, zero};
#pragma unroll
      for (int c = 0; c < 16; ++c) {
        bf16x8 a = qf[c];
#pragma unroll
        for (int nt = 0; nt < 2; ++nt) {
          int sr = nt * 16 + l16;
          bf16x8 fb = ld8(lK + sr * 512 + (((c * 4 + quad) ^ ksw) * 8));
          sacc[nt] = mfma16(a, fb, sacc[nt]);
        }
      }
#pragma unroll
      for (int nt = 0; nt < 2; ++nt) {
#pragma unroll
        for (int r = 0; r < 4; ++r) {
          float sv = sacc[nt][r] * scale;
          if (diag) {
            int sg = s0 + nt * 16 + l16;
            int tg = t0w + quad * 4 + r;
            sv = (sg > tg) ? -1e30f : sv;
          }
          sacc[nt][r] = sv;
        }
      }
      float mnew[4], alpha[4];
#pragma unroll
      for (int r = 0; r < 4; ++r) {
        float mx = fmaxf(sacc[0][r], sacc[1][r]);
        mx = fmaxf(mx, __shfl_xor(mx, 1));
        mx = fmaxf(mx, __shfl_xor(mx, 2));
        mx = fmaxf(mx, __shfl_xor(mx, 4));
        mx = fmaxf(mx, __shfl_xor(mx, 8));
        float mn = fmaxf(mrow[r], mx);
        alpha[r] = __expf(mrow[r] - mn);
        mnew[r] = mn;
        mrow[r] = mn;
      }
#pragma unroll
      for (int r = 0; r < 4; ++r) {
        float rs = 0.f;
#pragma unroll
        for (int nt = 0; nt < 2; ++nt) {
          float p = __expf(sacc[nt][r] - mnew[r]);  // masked -> exactly 0
          rs += p;
          myp[(quad * 4 + r) * 40 + nt * 16 + l16] = f2bf(p);
        }
        rs += __shfl_xor(rs, 1);
        rs += __shfl_xor(rs, 2);
        rs += __shfl_xor(rs, 4);
        rs += __shfl_xor(rs, 8);
        lrow[r] = lrow[r] * alpha[r] + rs;
      }
      // rescale acc only if some row's max moved (exact: alpha==1.0 when not)
      float amin = fminf(fminf(alpha[0], alpha[1]), fminf(alpha[2], alpha[3]));
      amin = fminf(amin, __shfl_xor(amin, 16));
      amin = fminf(amin, __shfl_xor(amin, 32));
      if (amin != 1.0f) {
#pragma unroll
        for (int nt = 0; nt < 32; ++nt)
#pragma unroll
          for (int r = 0; r < 4; ++r) acc[nt][r] *= alpha[r];
      }
      // P C-layout -> A-layout via wave-private LDS; V from LDS (staged)
      bf16x8 pf = ld8(myp + l16 * 40 + quad * 8);
#pragma unroll
      for (int nt = 0; nt < 32; ++nt) {
        int dr = nt * 16 + l16;
        bf16x8 vf = ld8(lV + dr * 32 + ((quad ^ vsw) * 8));
        acc[nt] = mfma16(pf, vf, acc[nt]);
      }
    }
    __syncthreads();  // all reads of chunk ch done; buffer free
    if (ch + 1 < c1) PART_STAGE(ch + 1);
  }

  // write partials: raw acc (bf16) + m,l per row
  u16* pj = pacc + (size_t)job * (64 * 512);
#pragma unroll
  for (int r = 0; r < 4; ++r) {
    int row = wave * 16 + quad * 4 + r;
    if (l16 == 0) {
      pml[job * 128 + row * 2 + 0] = mrow[r];
      pml[job * 128 + row * 2 + 1] = lrow[r];
    }
    u16* prow = pj + (size_t)row * 512;
#pragma unroll
    for (int nt = 0; nt < 32; ++nt)
      prow[nt * 16 + l16] = f2bf(acc[nt][r]);
  }
}

// ---- block reductions (256 threads = 4 waves)
__device__ __forceinline__ float blk_sum(float v, volatile float* red, int tid) {
#pragma unroll
  for (int o = 1; o < 64; o <<= 1) v += __shfl_xor(v, o);
  __syncthreads();
  if ((tid & 63) == 0) red[tid >> 6] = v;
  __syncthreads();
  return red[0] + red[1] + red[2] + red[3];
}

// ---- merge two s-halves + LayerNorm. One block per (b,t) row.
__global__ __launch_bounds__(256) void attn_merge(
    const u16* __restrict__ pacc, const float* __restrict__ pml,
    const float* __restrict__ gamma, const float* __restrict__ beta,
    float* __restrict__ out) {
  __shared__ float red[4];
  int t = blockIdx.x, b = blockIdx.y;
  int tid = threadIdx.x;
  int tt = t >> 6, row = t & 63;
  int jobA = (b * 32 + tt) * 2, jobB = jobA + 1;
  float mA = pml[jobA * 128 + row * 2], lA = pml[jobA * 128 + row * 2 + 1];
  float mB = pml[jobB * 128 + row * 2], lB = pml[jobB * 128 + row * 2 + 1];
  float m = fmaxf(mA, mB);
  float eA = __expf(mA - m), eB = __expf(mB - m);
  float invl = 1.0f / (eA * lA + eB * lB);
  const u16* pa = pacc + (size_t)jobA * (64 * 512) + (size_t)row * 512;
  const u16* pb = pacc + (size_t)jobB * (64 * 512) + (size_t)row * 512;
  int c0 = tid * 2;
  float o0 = (eA * bf2f(pa[c0]) + eB * bf2f(pb[c0])) * invl;
  float o1 = (eA * bf2f(pa[c0 + 1]) + eB * bf2f(pb[c0 + 1])) * invl;
  float s1 = blk_sum(o0 + o1, red, tid);
  __syncthreads();
  float s2 = blk_sum(o0 * o0 + o1 * o1, red, tid);
  float mu = s1 * (1.f / 512.f);
  float var = s2 * (1.f / 512.f) - mu * mu;
  float rstd = rsqrtf(var + 1e-5f);
  float* orow = out + ((size_t)b * ST + t) * SD;
  orow[c0]     = (o0 - mu) * rstd * gamma[c0] + beta[c0];
  orow[c0 + 1] = (o1 - mu) * rstd * gamma[c0 + 1] + beta[c0 + 1];
}

extern "C" void kernel_launch(void* const* d_in, const int* in_sizes, int n_in,
                              void* d_out, int out_size, void* d_ws, size_t ws_size,
                              hipStream_t stream) {
  (void)in_sizes; (void)n_in; (void)out_size; (void)ws_size;
  const float* x0 = (const float*)d_in[0];
  const float* x1 = (const float*)d_in[1];
  const float* Wq = (const float*)d_in[2];
  const float* Wk = (const float*)d_in[3];
  const float* Wv = (const float*)d_in[4];
  const float* gamma = (const float*)d_in[5];
  const float* beta = (const float*)d_in[6];
  u16* ws = (u16*)d_ws;
  u16* wt = ws;                                // 3*512*1024   ( 3.1 MB)
  u16* qb = wt + (size_t)3 * 512 * 1024;       // 16384*512    (16.8 MB)
  u16* kk = qb + (size_t)16384 * 512;          // 16384*512    (16.8 MB)
  u16* vt = kk + (size_t)16384 * 512;          // 8*512*2048   (16.8 MB)
  u16* xc = vt + (size_t)8 * 512 * 2048;       // 16384*1024   (33.6 MB)
  u16* pacc = xc;                              // reuse xc after qkv (same size)
  float* pml = (float*)wt;                     // reuse wt after qkv (0.26 MB)
  float* out = (float*)d_out;

  xcast<<<dim3(8192), dim3(256), 0, stream>>>(x0, x1, xc);
  wtrans<<<dim3(32, 16, 3), dim3(32, 8), 0, stream>>>(Wq, Wk, Wv, wt);
  qkv_m97<<<dim3(128, 12), dim3(256), 0, stream>>>(xc, wt, qb, kk, vt);
  attn_part<<<dim3(512), dim3(256), 0, stream>>>(qb, kk, vt, pacc, pml);
  attn_merge<<<dim3(2048, 8), dim3(256), 0, stream>>>(pacc, pml, gamma, beta, out);
}